// Round 6
// baseline (163.015 us; speedup 1.0000x reference)
//
#include <hip/hip_runtime.h>
#include <hip/hip_bf16.h>
#include <math.h>

// PAM fused attention, round 6: barrier-free attention. Each wave owns
// 16 queries x 32 channels x all 4096 keys; P transposes through WAVE-PRIVATE
// LDS scratch (in-order DS, lgkmcnt only, zero __syncthreads in the loop).
// Lesson R5: barrier-paced tiles serialize at ~2650 cyc/tile because every
// s_barrier drains vmcnt(0); removing the barrier is the structural fix.
// B=4, Cm=6, C=64, N=4096.

#define BATCH 4
#define CMAP  6
#define CH    64
#define NSP   4096
#define TN    64        // keys per tile
#define PSTR  72        // p_scr row stride (bf16): 144B rows, b128-aligned; reads 8-phase balanced

typedef __attribute__((ext_vector_type(8))) short short8;
typedef __attribute__((ext_vector_type(4))) float f32x4;

#if __has_builtin(__builtin_amdgcn_exp2f)
#define EXP2(x) __builtin_amdgcn_exp2f(x)
#else
#define EXP2(x) exp2f(x)
#endif

__device__ __forceinline__ unsigned f2bf(float f) {      // RNE f32->bf16 bits
    unsigned u = __float_as_uint(f);
    return (u + 0x7fffu + ((u >> 16) & 1u)) >> 16;
}

#define INVLN2 1.44269504088896f
#define SHIFT_BF16 0xC238u   /* bf16(-46.0): fixed softmax shift (exact, cancels) */
#define ONE_BF16   0x3F80u

// ---------------- kernel 1: all projections fused ----------------
// grid (NSP/64, 2, BATCH), block 256. Each wave: 8 output channels.
__global__ void proj_kernel(const float* __restrict__ map1, const float* __restrict__ map2,
                            const float* __restrict__ fm,
                            const float* __restrict__ wb, const float* __restrict__ bb,
                            const float* __restrict__ wc, const float* __restrict__ bc,
                            const float* __restrict__ wd, const float* __restrict__ bd,
                            unsigned short* __restrict__ featq8,
                            unsigned short* __restrict__ featk8,
                            unsigned short* __restrict__ featd)
{
    const int b    = blockIdx.z;
    const int half = blockIdx.y;
    const int n    = blockIdx.x * 64 + (threadIdx.x & 63);
    const int og   = threadIdx.x >> 6;

    // ---- V projection: 8 channels per wave
    float vals[CH];
#pragma unroll
    for (int c = 0; c < CH; ++c)
        vals[c] = fm[(size_t)(b*CH + c)*NSP + n];
#pragma unroll
    for (int oi = 0; oi < 8; ++oi) {
        const int o = half*32 + og*8 + oi;
        float a = bd[o];
#pragma unroll
        for (int c = 0; c < CH; ++c)
            a = fmaf(vals[c], wd[o*CH + c], a);
        featd[(size_t)(b*CH + o)*NSP + n] = (unsigned short)f2bf(a);
    }

    // ---- Q/K fragment rows (one wave per (x,b))
    if (half == 0 && og == 0) {
        float v1[CMAP], v2[CMAP];
#pragma unroll
        for (int c = 0; c < CMAP; ++c) {
            v1[c] = map1[(size_t)(b*CMAP + c)*NSP + n];
            v2[c] = map2[(size_t)(b*CMAP + c)*NSP + n];
        }
        unsigned qv[CMAP], kv[CMAP];
#pragma unroll
        for (int o = 0; o < CMAP; ++o) {
            float a1 = bb[o], a2 = bc[o];
#pragma unroll
            for (int c = 0; c < CMAP; ++c) {
                a1 = fmaf(v1[c], wb[o*CMAP + c], a1);
                a2 = fmaf(v2[c], wc[o*CMAP + c], a2);
            }
            qv[o] = f2bf(a1 * INVLN2);
            kv[o] = f2bf(a2);
        }
        uint4 qw, kw;
        qw.x = qv[0] | (qv[1] << 16);
        qw.y = qv[2] | (qv[3] << 16);
        qw.z = qv[4] | (qv[5] << 16);
        qw.w = SHIFT_BF16;                       // slot6 = -46, slot7 = 0
        kw.x = kv[0] | (kv[1] << 16);
        kw.y = kv[2] | (kv[3] << 16);
        kw.z = kv[4] | (kv[5] << 16);
        kw.w = ONE_BF16;                         // slot6 = 1, slot7 = 0
        *(uint4*)&featq8[(size_t)(b*NSP + n)*8] = qw;
        *(uint4*)&featk8[(size_t)(b*NSP + n)*8] = kw;
    }
}

// ---------------- kernel 2: barrier-free attention ----------------
// grid (NSP/64=64, 2, BATCH) = 512 blocks -> 2 blocks/CU, 8 waves/CU.
// Wave = 16 queries x 32 channels x 4096 keys. LDS 18.7 KB/block.
__global__ __launch_bounds__(256, 2)
void attn_kernel(const unsigned short* __restrict__ featq8,
                 const unsigned short* __restrict__ featk8,
                 const unsigned short* __restrict__ featd,
                 const float* __restrict__ fm, const float* __restrict__ alpha_p,
                 float* __restrict__ out)
{
    __shared__ unsigned short p_scr[2][4][16*PSTR];  // [buf][wave][q][m] wave-private
    __shared__ float l_scr[4][16];

    const int b    = blockIdx.z;
    const int chh  = blockIdx.y;                   // 32-channel half
    const int t    = threadIdx.x;
    const int lane = t & 63, w = t >> 6;
    const int row16 = lane & 15, quad = lane >> 4;
    const int n0w  = blockIdx.x * 64 + w * 16;     // this wave's 16 queries

    // Q B-frag: B[k=quad*8+j][q=row16]; quads 1-3 MUST be zero (kills the
    // k>=8 garbage that the unguarded K loads pick up from neighboring rows).
    short8 qf = {0,0,0,0,0,0,0,0};
    if (quad == 0)
        qf = *(const short8*)&featq8[(size_t)(b*NSP + n0w + row16)*8];

    // K A-frag stream: A[m = m0+mb*16+row16][k' = quad*8+j]. Unguarded: for
    // quad>=1 this reads the next rows' data (finite, valid memory) — zeroed
    // Q slots make those products exactly 0.
    const unsigned short* kbase = featk8 + ((size_t)b*NSP + row16)*8 + quad*8;
    // V B-frag stream: B[k'=quad*8+j -> m][ch = chh*32 + cb*16 + row16]
    const unsigned short* vb0 = featd + ((size_t)(b*CH + chh*32 + row16))*NSP + quad*8;
    const unsigned short* vb1 = vb0 + 16*NSP;

    // tile-0 fragments
    short8 k0 = *(const short8*)(kbase +  0*8);
    short8 k1 = *(const short8*)(kbase + 16*8);
    short8 k2 = *(const short8*)(kbase + 32*8);
    short8 k3 = *(const short8*)(kbase + 48*8);
    short8 v00 = *(const short8*)(vb0);        // cb0, m 0..31
    short8 v01 = *(const short8*)(vb0 + 32);   // cb0, m 32..63
    short8 v10 = *(const short8*)(vb1);        // cb1, m 0..31
    short8 v11 = *(const short8*)(vb1 + 32);   // cb1, m 32..63

    const f32x4 zf = {0.f,0.f,0.f,0.f};
    f32x4 acc0 = zf, acc1 = zf;
    float lacc = 0.f;

    unsigned short* const pw_base = &p_scr[0][w][0] ;  // parity handled below
    const int prow = row16 * PSTR;

#pragma unroll 2
    for (int tile = 0; tile < NSP/TN; ++tile) {
        // ---- scores: S^T[m][q] for all 4 m-blocks of this 64-key tile
        f32x4 s0 = __builtin_amdgcn_mfma_f32_16x16x32_bf16(k0, qf, zf, 0, 0, 0);
        f32x4 s1 = __builtin_amdgcn_mfma_f32_16x16x32_bf16(k1, qf, zf, 0, 0, 0);
        f32x4 s2 = __builtin_amdgcn_mfma_f32_16x16x32_bf16(k2, qf, zf, 0, 0, 0);
        f32x4 s3 = __builtin_amdgcn_mfma_f32_16x16x32_bf16(k3, qf, zf, 0, 0, 0);

        // ---- prefetch next tile's K/V frags (no barrier -> drains at use)
        const int m1 = ((tile + 1) & (NSP/TN - 1)) * TN;
        const short8 k0n = *(const short8*)(kbase + (m1 +  0)*8);
        const short8 k1n = *(const short8*)(kbase + (m1 + 16)*8);
        const short8 k2n = *(const short8*)(kbase + (m1 + 32)*8);
        const short8 k3n = *(const short8*)(kbase + (m1 + 48)*8);
        const short8 v00n = *(const short8*)(vb0 + m1);
        const short8 v01n = *(const short8*)(vb0 + m1 + 32);
        const short8 v10n = *(const short8*)(vb1 + m1);
        const short8 v11n = *(const short8*)(vb1 + m1 + 32);

        // ---- p = exp2(s) -> pack bf16 -> wave-private LDS (C-layout:
        // lane holds S^T[m=4*quad+r][q=row16] for m-block mb)
        unsigned short* pw = &p_scr[tile & 1][w][prow + quad*4];
#define PAM_DO(mb, sv)                                                          \
        {                                                                       \
            const float p0 = EXP2(sv[0]), p1 = EXP2(sv[1]);                     \
            const float p2 = EXP2(sv[2]), p3 = EXP2(sv[3]);                     \
            lacc += (p0 + p1) + (p2 + p3);                                      \
            uint2 pp;                                                           \
            pp.x = __builtin_amdgcn_perm(__float_as_uint(p1), __float_as_uint(p0), 0x07060302u); \
            pp.y = __builtin_amdgcn_perm(__float_as_uint(p3), __float_as_uint(p2), 0x07060302u); \
            *(uint2*)(pw + mb*16) = pp;                                         \
        }
        PAM_DO(0, s0) PAM_DO(1, s1) PAM_DO(2, s2) PAM_DO(3, s3)
#undef PAM_DO

        // ---- A-frags back from LDS (in-order DS: reads see this wave's writes)
        const unsigned short* pr = &p_scr[tile & 1][w][prow + quad*8];
        const short8 a0 = *(const short8*)pr;          // m 0..31
        const short8 a1 = *(const short8*)(pr + 32);   // m 32..63

        // ---- PV: D[q][ch] += P[q][m] * V[m][ch]
        acc0 = __builtin_amdgcn_mfma_f32_16x16x32_bf16(a0, v00, acc0, 0, 0, 0);
        acc0 = __builtin_amdgcn_mfma_f32_16x16x32_bf16(a1, v01, acc0, 0, 0, 0);
        acc1 = __builtin_amdgcn_mfma_f32_16x16x32_bf16(a0, v10, acc1, 0, 0, 0);
        acc1 = __builtin_amdgcn_mfma_f32_16x16x32_bf16(a1, v11, acc1, 0, 0, 0);

        k0 = k0n; k1 = k1n; k2 = k2n; k3 = k3n;
        v00 = v00n; v01 = v01n; v10 = v10n; v11 = v11n;
    }
    (void)pw_base;

    // ---- l[q]: lane holds partial over its m's; sum lanes q, q+16, q+32, q+48
    lacc += __shfl_xor(lacc, 16);
    lacc += __shfl_xor(lacc, 32);
    if (quad == 0) l_scr[w][row16] = lacc;             // in-wave LDS, no barrier
    const float4 lv = *(const float4*)&l_scr[w][quad*4];

    // ---- epilogue: D layout col=row16=ch-offset, row=quad*4+reg=query-offset
    const float alpha = alpha_p[0];
    const float c0 = alpha / (lv.x + 1e-30f);
    const float c1 = alpha / (lv.y + 1e-30f);
    const float c2 = alpha / (lv.z + 1e-30f);
    const float c3 = alpha / (lv.w + 1e-30f);
#pragma unroll
    for (int cb = 0; cb < 2; ++cb) {
        const int ch = chh*32 + cb*16 + row16;
        const size_t base = (size_t)(b*CH + ch)*NSP + n0w + quad*4;
        const float4 f = *(const float4*)&fm[base];
        const f32x4 a = cb ? acc1 : acc0;
        float4 o;
        o.x = fmaf(c0, a[0], f.x);
        o.y = fmaf(c1, a[1], f.y);
        o.z = fmaf(c2, a[2], f.z);
        o.w = fmaf(c3, a[3], f.w);
        *(float4*)&out[base] = o;
    }
}

// ---------------- launcher ----------------
extern "C" void kernel_launch(void* const* d_in, const int* in_sizes, int n_in,
                              void* d_out, int out_size, void* d_ws, size_t ws_size,
                              hipStream_t stream)
{
    const float* map1  = (const float*)d_in[0];
    const float* map2  = (const float*)d_in[1];
    const float* fm    = (const float*)d_in[2];
    const float* wb    = (const float*)d_in[3];
    const float* bb    = (const float*)d_in[4];
    const float* wc    = (const float*)d_in[5];
    const float* bc    = (const float*)d_in[6];
    const float* wd    = (const float*)d_in[7];
    const float* bd    = (const float*)d_in[8];
    const float* alpha = (const float*)d_in[9];
    float* out = (float*)d_out;

    // ws: featq8 bf16 [4][4096][8] 256KB | featk8 256KB | featd bf16 [4][64][4096] 2MB
    unsigned short* featq8 = (unsigned short*)d_ws;
    unsigned short* featk8 = featq8 + (size_t)BATCH*NSP*8;
    unsigned short* featd  = featk8 + (size_t)BATCH*NSP*8;

    proj_kernel<<<dim3(NSP/64, 2, BATCH), 256, 0, stream>>>(
        map1, map2, fm, wb, bb, wc, bc, wd, bd, featq8, featk8, featd);
    attn_kernel<<<dim3(NSP/64, 2, BATCH), 256, 0, stream>>>(
        featq8, featk8, featd, fm, alpha, out);
}

// Round 7
// 125.485 us; speedup vs baseline: 1.2991x; 1.2991x over previous
//
#include <hip/hip_runtime.h>
#include <hip/hip_bf16.h>
#include <math.h>

// PAM fused attention, round 7: fragment-ready V layout.
// Diagnosis R2-R6: V B-frag loads strided 8KB across 16 lanes -> all lines in
// ONE L1 set (32KB/64-set L1) -> set thrash, ~16 serialized L2 fills per load,
// ~3000 cyc/tile regardless of barriers/occupancy. Fix: proj writes V
// pre-swizzled in MFMA B-fragment order; attn V loads become coalesced 1KB
// wave loads. B=4, Cm=6, C=64, N=4096.

#define BATCH 4
#define CMAP  6
#define CH    64
#define NSP   4096
#define TN    64        // keys per tile
#define PSTR  72        // p_scr row stride (bf16)

typedef __attribute__((ext_vector_type(8))) short short8;
typedef __attribute__((ext_vector_type(4))) float f32x4;

#if __has_builtin(__builtin_amdgcn_exp2f)
#define EXP2(x) __builtin_amdgcn_exp2f(x)
#else
#define EXP2(x) exp2f(x)
#endif

__device__ __forceinline__ unsigned f2bf(float f) {      // RNE f32->bf16 bits
    unsigned u = __float_as_uint(f);
    return (u + 0x7fffu + ((u >> 16) & 1u)) >> 16;
}

#define INVLN2 1.44269504088896f
#define SHIFT_BF16 0xC238u   /* bf16(-46.0): fixed softmax shift (exact, cancels) */
#define ONE_BF16   0x3F80u

// V fragment layout: featdf[b][ht(128)][cb(4)][512]
//   half-tile ht = 32 keys; cb = 16-channel block.
//   Within a 512-elem frag: elem ((quad*16 + r)*8 + j) = V[m=ht*32+quad*8+j][ch=cb*16+r]
//   so MFMA lane l=(quad*16+row16) loads its B-frag 16B at frag_base + l*8 elems.

// ---------------- kernel 1: projections + V fragment transpose ----------------
// grid (NSP/64, 2, BATCH), block 256. Each wave: 8 channels of the half.
__global__ void proj_kernel(const float* __restrict__ map1, const float* __restrict__ map2,
                            const float* __restrict__ fm,
                            const float* __restrict__ wb, const float* __restrict__ bb,
                            const float* __restrict__ wc, const float* __restrict__ bc,
                            const float* __restrict__ wd, const float* __restrict__ bd,
                            unsigned short* __restrict__ featq8,
                            unsigned short* __restrict__ featk8,
                            unsigned short* __restrict__ featdf)
{
    __shared__ unsigned short vfrag[2048];   // [ht(2)][cb_local(2)][512] = 4KB

    const int b    = blockIdx.z;
    const int half = blockIdx.y;
    const int lane = threadIdx.x & 63;
    const int og   = threadIdx.x >> 6;
    const int n    = blockIdx.x * 64 + lane;

    // ---- V projection: 8 channels per wave -> LDS in fragment order
    const int ht = lane >> 5;                 // half-tile within block
    const int mm = lane & 31;
    const int q4 = mm >> 3, jj = mm & 7;
    const int cb_local = og >> 1;
    float vals[CH];
#pragma unroll
    for (int c = 0; c < CH; ++c)
        vals[c] = fm[(size_t)(b*CH + c)*NSP + n];
#pragma unroll
    for (int oi = 0; oi < 8; ++oi) {
        const int o = half*32 + og*8 + oi;
        float a = bd[o];
#pragma unroll
        for (int c = 0; c < CH; ++c)
            a = fmaf(vals[c], wd[o*CH + c], a);
        const int r = (og & 1)*8 + oi;        // ch & 15
        vfrag[(ht*2 + cb_local)*512 + (q4*16 + r)*8 + jj] = (unsigned short)f2bf(a);
    }

    // ---- Q/K fragment rows (one wave per (x,b))
    if (half == 0 && og == 0) {
        float v1[CMAP], v2[CMAP];
#pragma unroll
        for (int c = 0; c < CMAP; ++c) {
            v1[c] = map1[(size_t)(b*CMAP + c)*NSP + n];
            v2[c] = map2[(size_t)(b*CMAP + c)*NSP + n];
        }
        unsigned qv[CMAP], kv[CMAP];
#pragma unroll
        for (int o = 0; o < CMAP; ++o) {
            float a1 = bb[o], a2 = bc[o];
#pragma unroll
            for (int c = 0; c < CMAP; ++c) {
                a1 = fmaf(v1[c], wb[o*CMAP + c], a1);
                a2 = fmaf(v2[c], wc[o*CMAP + c], a2);
            }
            qv[o] = f2bf(a1 * INVLN2);
            kv[o] = f2bf(a2);
        }
        uint4 qw, kw;
        qw.x = qv[0] | (qv[1] << 16);
        qw.y = qv[2] | (qv[3] << 16);
        qw.z = qv[4] | (qv[5] << 16);
        qw.w = SHIFT_BF16;                       // slot6 = -46, slot7 = 0
        kw.x = kv[0] | (kv[1] << 16);
        kw.y = kv[2] | (kv[3] << 16);
        kw.z = kv[4] | (kv[5] << 16);
        kw.w = ONE_BF16;                         // slot6 = 1, slot7 = 0
        *(uint4*)&featq8[(size_t)(b*NSP + n)*8] = qw;
        *(uint4*)&featk8[(size_t)(b*NSP + n)*8] = kw;
    }

    __syncthreads();

    // ---- fragment write-out: contiguous LDS read, coalesced global store
    {
        const int tt = threadIdx.x;
        const uint4 d = *(const uint4*)&vfrag[tt*8];
        const int ht2 = tt >> 7, inner = tt & 127;
        const size_t off = (((size_t)(b*128 + blockIdx.x*2 + ht2)*4) + half*2)*512
                         + (size_t)inner*8;
        *(uint4*)&featdf[off] = d;
    }
}

// ---------------- kernel 2: barrier-free attention, coalesced V frags --------
// grid (NSP/64=64, 2, BATCH) = 512 blocks -> 2 blocks/CU, 8 waves/CU.
// Wave = 16 queries x 32 channels x 4096 keys. LDS 18.5 KB/block.
__global__ __launch_bounds__(256, 2)
void attn_kernel(const unsigned short* __restrict__ featq8,
                 const unsigned short* __restrict__ featk8,
                 const unsigned short* __restrict__ featdf,
                 const float* __restrict__ fm, const float* __restrict__ alpha_p,
                 float* __restrict__ out)
{
    __shared__ unsigned short p_scr[2][4][16*PSTR];  // [buf][wave][q][m] wave-private
    __shared__ float l_scr[4][16];

    const int b    = blockIdx.z;
    const int chh  = blockIdx.y;                   // 32-channel half
    const int t    = threadIdx.x;
    const int lane = t & 63, w = t >> 6;
    const int row16 = lane & 15, quad = lane >> 4;
    const int n0w  = blockIdx.x * 64 + w * 16;     // this wave's 16 queries

    // Q B-frag: B[k=quad*8+j][q=row16]; quads 1-3 zero (kills unguarded-K garbage)
    short8 qf = {0,0,0,0,0,0,0,0};
    if (quad == 0)
        qf = *(const short8*)&featq8[(size_t)(b*NSP + n0w + row16)*8];

    // K A-frag stream: A[m][k'=quad*8+j]; quad>=1 reads neighbor rows (finite),
    // zeroed Q slots null those products.
    const unsigned short* kbase = featk8 + ((size_t)b*NSP + row16)*8 + quad*8;
    // V fragment stream: coalesced, lane*16B within each 1KB frag.
    const unsigned short* vfb = featdf + ((size_t)b*128*4)*512 + lane*8;
    const int cb0 = chh*2, cb1 = chh*2 + 1;

    // tile-0 fragments
    short8 k0 = *(const short8*)(kbase +  0*8);
    short8 k1 = *(const short8*)(kbase + 16*8);
    short8 k2 = *(const short8*)(kbase + 32*8);
    short8 k3 = *(const short8*)(kbase + 48*8);
    short8 v00 = *(const short8*)(vfb + (size_t)(0*4 + cb0)*512);  // ht0, cb0 (m 0..31)
    short8 v01 = *(const short8*)(vfb + (size_t)(1*4 + cb0)*512);  // ht1, cb0 (m 32..63)
    short8 v10 = *(const short8*)(vfb + (size_t)(0*4 + cb1)*512);  // ht0, cb1
    short8 v11 = *(const short8*)(vfb + (size_t)(1*4 + cb1)*512);  // ht1, cb1

    const f32x4 zf = {0.f,0.f,0.f,0.f};
    f32x4 acc0 = zf, acc1 = zf;
    float lacc = 0.f;
    const int prow = row16 * PSTR;

#pragma unroll 2
    for (int tile = 0; tile < NSP/TN; ++tile) {
        // ---- scores: S^T[m][q] for all 4 m-blocks of this 64-key tile
        f32x4 s0 = __builtin_amdgcn_mfma_f32_16x16x32_bf16(k0, qf, zf, 0, 0, 0);
        f32x4 s1 = __builtin_amdgcn_mfma_f32_16x16x32_bf16(k1, qf, zf, 0, 0, 0);
        f32x4 s2 = __builtin_amdgcn_mfma_f32_16x16x32_bf16(k2, qf, zf, 0, 0, 0);
        f32x4 s3 = __builtin_amdgcn_mfma_f32_16x16x32_bf16(k3, qf, zf, 0, 0, 0);

        // ---- prefetch next tile's K/V frags (wraps; no barrier, drains at use)
        const int tn = (tile + 1) & (NSP/TN - 1);
        const int m1 = tn * TN;
        const short8 k0n = *(const short8*)(kbase + (m1 +  0)*8);
        const short8 k1n = *(const short8*)(kbase + (m1 + 16)*8);
        const short8 k2n = *(const short8*)(kbase + (m1 + 32)*8);
        const short8 k3n = *(const short8*)(kbase + (m1 + 48)*8);
        const short8 v00n = *(const short8*)(vfb + (size_t)((tn*2 + 0)*4 + cb0)*512);
        const short8 v01n = *(const short8*)(vfb + (size_t)((tn*2 + 1)*4 + cb0)*512);
        const short8 v10n = *(const short8*)(vfb + (size_t)((tn*2 + 0)*4 + cb1)*512);
        const short8 v11n = *(const short8*)(vfb + (size_t)((tn*2 + 1)*4 + cb1)*512);

        // ---- p = exp2(s) -> pack bf16 -> wave-private LDS
        // (C-layout: lane holds S^T[m = mb*16 + quad*4 + r][q = row16])
        unsigned short* pw = &p_scr[tile & 1][w][prow + quad*4];
#define PAM_DO(mb, sv)                                                          \
        {                                                                       \
            const float p0 = EXP2(sv[0]), p1 = EXP2(sv[1]);                     \
            const float p2 = EXP2(sv[2]), p3 = EXP2(sv[3]);                     \
            lacc += (p0 + p1) + (p2 + p3);                                      \
            uint2 pp;                                                           \
            pp.x = __builtin_amdgcn_perm(__float_as_uint(p1), __float_as_uint(p0), 0x07060302u); \
            pp.y = __builtin_amdgcn_perm(__float_as_uint(p3), __float_as_uint(p2), 0x07060302u); \
            *(uint2*)(pw + mb*16) = pp;                                         \
        }
        PAM_DO(0, s0) PAM_DO(1, s1) PAM_DO(2, s2) PAM_DO(3, s3)
#undef PAM_DO

        // ---- A-frags back from LDS (in-order DS within the wave)
        const unsigned short* pr = &p_scr[tile & 1][w][prow + quad*8];
        const short8 a0 = *(const short8*)pr;          // m 0..31
        const short8 a1 = *(const short8*)(pr + 32);   // m 32..63

        // ---- PV: D[q][ch] += P[q][m] * V[m][ch]
        acc0 = __builtin_amdgcn_mfma_f32_16x16x32_bf16(a0, v00, acc0, 0, 0, 0);
        acc0 = __builtin_amdgcn_mfma_f32_16x16x32_bf16(a1, v01, acc0, 0, 0, 0);
        acc1 = __builtin_amdgcn_mfma_f32_16x16x32_bf16(a0, v10, acc1, 0, 0, 0);
        acc1 = __builtin_amdgcn_mfma_f32_16x16x32_bf16(a1, v11, acc1, 0, 0, 0);

        k0 = k0n; k1 = k1n; k2 = k2n; k3 = k3n;
        v00 = v00n; v01 = v01n; v10 = v10n; v11 = v11n;
    }

    // ---- l[q]: sum lane partials over m; lanes q, q+16, q+32, q+48
    lacc += __shfl_xor(lacc, 16);
    lacc += __shfl_xor(lacc, 32);
    if (quad == 0) l_scr[w][row16] = lacc;             // in-wave LDS, no barrier
    const float4 lv = *(const float4*)&l_scr[w][quad*4];

    // ---- epilogue: D layout col=row16=ch-offset, row=quad*4+reg=query-offset
    const float alpha = alpha_p[0];
    const float c0 = alpha / (lv.x + 1e-30f);
    const float c1 = alpha / (lv.y + 1e-30f);
    const float c2 = alpha / (lv.z + 1e-30f);
    const float c3 = alpha / (lv.w + 1e-30f);
#pragma unroll
    for (int cb = 0; cb < 2; ++cb) {
        const int ch = chh*32 + cb*16 + row16;
        const size_t base = (size_t)(b*CH + ch)*NSP + n0w + quad*4;
        const float4 f = *(const float4*)&fm[base];
        const f32x4 a = cb ? acc1 : acc0;
        float4 o;
        o.x = fmaf(c0, a[0], f.x);
        o.y = fmaf(c1, a[1], f.y);
        o.z = fmaf(c2, a[2], f.z);
        o.w = fmaf(c3, a[3], f.w);
        *(float4*)&out[base] = o;
    }
}

// ---------------- launcher ----------------
extern "C" void kernel_launch(void* const* d_in, const int* in_sizes, int n_in,
                              void* d_out, int out_size, void* d_ws, size_t ws_size,
                              hipStream_t stream)
{
    const float* map1  = (const float*)d_in[0];
    const float* map2  = (const float*)d_in[1];
    const float* fm    = (const float*)d_in[2];
    const float* wb    = (const float*)d_in[3];
    const float* bb    = (const float*)d_in[4];
    const float* wc    = (const float*)d_in[5];
    const float* bc    = (const float*)d_in[6];
    const float* wd    = (const float*)d_in[7];
    const float* bd    = (const float*)d_in[8];
    const float* alpha = (const float*)d_in[9];
    float* out = (float*)d_out;

    // ws: featq8 bf16 [4][4096][8] 256KB | featk8 256KB | featdf frag 2MB
    unsigned short* featq8 = (unsigned short*)d_ws;
    unsigned short* featk8 = featq8 + (size_t)BATCH*NSP*8;
    unsigned short* featdf = featk8 + (size_t)BATCH*NSP*8;

    proj_kernel<<<dim3(NSP/64, 2, BATCH), 256, 0, stream>>>(
        map1, map2, fm, wb, bb, wc, bc, wd, bd, featq8, featk8, featdf);
    attn_kernel<<<dim3(NSP/64, 2, BATCH), 256, 0, stream>>>(
        featq8, featk8, featdf, fm, alpha, out);
}

// Round 8
// 122.634 us; speedup vs baseline: 1.3293x; 1.0232x over previous
//
#include <hip/hip_runtime.h>
#include <hip/hip_bf16.h>
#include <math.h>

// PAM fused attention, round 8: R7 (fragment-ready V, barrier-free) + explicit
// software pipeline: PV lags scores by one tile, so the LDS P write->read
// round-trip of tile t is covered by a full iteration of independent work.
// Layouts are byte-identical to R7 (verified passing). B=4, Cm=6, C=64, N=4096.

#define BATCH 4
#define CMAP  6
#define CH    64
#define NSP   4096
#define TN    64        // keys per tile
#define PSTR  72        // p_scr row stride (bf16)

typedef __attribute__((ext_vector_type(8))) short short8;
typedef __attribute__((ext_vector_type(4))) float f32x4;

#if __has_builtin(__builtin_amdgcn_exp2f)
#define EXP2(x) __builtin_amdgcn_exp2f(x)
#else
#define EXP2(x) exp2f(x)
#endif

__device__ __forceinline__ unsigned f2bf(float f) {      // RNE f32->bf16 bits
    unsigned u = __float_as_uint(f);
    return (u + 0x7fffu + ((u >> 16) & 1u)) >> 16;
}

#define INVLN2 1.44269504088896f
#define SHIFT_BF16 0xC238u   /* bf16(-46.0): fixed softmax shift (exact, cancels) */
#define ONE_BF16   0x3F80u

// V fragment layout: featdf[b][ht(128)][cb(4)][512]
//   half-tile ht = 32 keys; cb = 16-channel block.
//   elem ((quad*16 + r)*8 + j) = V[m=ht*32+quad*8+j][ch=cb*16+r]
//   -> MFMA lane l=(quad*16+row16) loads its 16B at frag_base + l*8 elems.

// ---------------- kernel 1: projections + V fragment transpose ----------------
// grid (NSP/64, 2, BATCH), block 256. Each wave: 8 channels of the half.
__global__ void proj_kernel(const float* __restrict__ map1, const float* __restrict__ map2,
                            const float* __restrict__ fm,
                            const float* __restrict__ wb, const float* __restrict__ bb,
                            const float* __restrict__ wc, const float* __restrict__ bc,
                            const float* __restrict__ wd, const float* __restrict__ bd,
                            unsigned short* __restrict__ featq8,
                            unsigned short* __restrict__ featk8,
                            unsigned short* __restrict__ featdf)
{
    __shared__ unsigned short vfrag[2048];   // [ht(2)][cb_local(2)][512] = 4KB

    const int b    = blockIdx.z;
    const int half = blockIdx.y;
    const int lane = threadIdx.x & 63;
    const int og   = threadIdx.x >> 6;
    const int n    = blockIdx.x * 64 + lane;

    // ---- V projection: 8 channels per wave -> LDS in fragment order
    const int ht = lane >> 5;                 // half-tile within block
    const int mm = lane & 31;
    const int q4 = mm >> 3, jj = mm & 7;
    const int cb_local = og >> 1;
    float vals[CH];
#pragma unroll
    for (int c = 0; c < CH; ++c)
        vals[c] = fm[(size_t)(b*CH + c)*NSP + n];
#pragma unroll
    for (int oi = 0; oi < 8; ++oi) {
        const int o = half*32 + og*8 + oi;
        float a = bd[o];
#pragma unroll
        for (int c = 0; c < CH; ++c)
            a = fmaf(vals[c], wd[o*CH + c], a);
        const int r = (og & 1)*8 + oi;        // ch & 15
        vfrag[(ht*2 + cb_local)*512 + (q4*16 + r)*8 + jj] = (unsigned short)f2bf(a);
    }

    // ---- Q/K fragment rows (one wave per (x,b))
    if (half == 0 && og == 0) {
        float v1[CMAP], v2[CMAP];
#pragma unroll
        for (int c = 0; c < CMAP; ++c) {
            v1[c] = map1[(size_t)(b*CMAP + c)*NSP + n];
            v2[c] = map2[(size_t)(b*CMAP + c)*NSP + n];
        }
        unsigned qv[CMAP], kv[CMAP];
#pragma unroll
        for (int o = 0; o < CMAP; ++o) {
            float a1 = bb[o], a2 = bc[o];
#pragma unroll
            for (int c = 0; c < CMAP; ++c) {
                a1 = fmaf(v1[c], wb[o*CMAP + c], a1);
                a2 = fmaf(v2[c], wc[o*CMAP + c], a2);
            }
            qv[o] = f2bf(a1 * INVLN2);
            kv[o] = f2bf(a2);
        }
        uint4 qw, kw;
        qw.x = qv[0] | (qv[1] << 16);
        qw.y = qv[2] | (qv[3] << 16);
        qw.z = qv[4] | (qv[5] << 16);
        qw.w = SHIFT_BF16;                       // slot6 = -46, slot7 = 0
        kw.x = kv[0] | (kv[1] << 16);
        kw.y = kv[2] | (kv[3] << 16);
        kw.z = kv[4] | (kv[5] << 16);
        kw.w = ONE_BF16;                         // slot6 = 1, slot7 = 0
        *(uint4*)&featq8[(size_t)(b*NSP + n)*8] = qw;
        *(uint4*)&featk8[(size_t)(b*NSP + n)*8] = kw;
    }

    __syncthreads();

    // ---- fragment write-out: contiguous LDS read, coalesced global store
    {
        const int tt = threadIdx.x;
        const uint4 d = *(const uint4*)&vfrag[tt*8];
        const int ht2 = tt >> 7, inner = tt & 127;
        const size_t off = (((size_t)(b*128 + blockIdx.x*2 + ht2)*4) + half*2)*512
                         + (size_t)inner*8;
        *(uint4*)&featdf[off] = d;
    }
}

// ---------------- kernel 2: barrier-free attention, software-pipelined -------
// grid (NSP/64=64, 2, BATCH) = 512 blocks -> 2 blocks/CU, 8 waves/CU.
// Wave = 16 queries x 32 channels x 4096 keys. LDS 18.5 KB/block.
__global__ __launch_bounds__(256, 2)
void attn_kernel(const unsigned short* __restrict__ featq8,
                 const unsigned short* __restrict__ featk8,
                 const unsigned short* __restrict__ featdf,
                 const float* __restrict__ fm, const float* __restrict__ alpha_p,
                 float* __restrict__ out)
{
    __shared__ unsigned short p_scr[2][4][16*PSTR];  // [buf][wave][q][m] wave-private
    __shared__ float l_scr[4][16];

    const int b    = blockIdx.z;
    const int chh  = blockIdx.y;                   // 32-channel half
    const int t    = threadIdx.x;
    const int lane = t & 63, w = t >> 6;
    const int row16 = lane & 15, quad = lane >> 4;
    const int n0w  = blockIdx.x * 64 + w * 16;     // this wave's 16 queries

    // Q B-frag: B[k=quad*8+j][q=row16]; quads 1-3 zero (kills unguarded-K garbage)
    short8 qf = {0,0,0,0,0,0,0,0};
    if (quad == 0)
        qf = *(const short8*)&featq8[(size_t)(b*NSP + n0w + row16)*8];

    // K A-frag stream: A[m][k'=quad*8+j]; quad>=1 reads neighbor rows (finite),
    // zeroed Q slots null those products.
    const unsigned short* kbase = featk8 + ((size_t)b*NSP + row16)*8 + quad*8;
    // V fragment stream: coalesced, lane*16B within each 1KB frag.
    const unsigned short* vfb = featdf + ((size_t)b*128*4)*512 + lane*8;
    const int cb0 = chh*2, cb1 = chh*2 + 1;

    const f32x4 zf = {0.f,0.f,0.f,0.f};
    f32x4 acc0 = zf, acc1 = zf;
    float lacc = 0.f;
    const int prow = row16 * PSTR;

    // exp -> pack bf16 -> wave-private LDS write for one m-block.
    // C-layout: lane holds S^T[m = mb*16 + quad*4 + r][q = row16].
#define PAM_DO(pwp, mb, sv)                                                     \
    {                                                                           \
        const float p0 = EXP2(sv[0]), p1 = EXP2(sv[1]);                         \
        const float p2 = EXP2(sv[2]), p3 = EXP2(sv[3]);                         \
        lacc += (p0 + p1) + (p2 + p3);                                          \
        uint2 pp;                                                               \
        pp.x = __builtin_amdgcn_perm(__float_as_uint(p1), __float_as_uint(p0), 0x07060302u); \
        pp.y = __builtin_amdgcn_perm(__float_as_uint(p3), __float_as_uint(p2), 0x07060302u); \
        *(uint2*)((pwp) + (mb)*16) = pp;                                        \
    }

    // ---------------- pipeline prologue: tile 0 ----------------
    short8 k0 = *(const short8*)(kbase +  0*8);
    short8 k1 = *(const short8*)(kbase + 16*8);
    short8 k2 = *(const short8*)(kbase + 32*8);
    short8 k3 = *(const short8*)(kbase + 48*8);
    // V(0) into "next" set
    short8 vn0 = *(const short8*)(vfb + (size_t)(0*4 + cb0)*512);
    short8 vn1 = *(const short8*)(vfb + (size_t)(1*4 + cb0)*512);
    short8 vn2 = *(const short8*)(vfb + (size_t)(0*4 + cb1)*512);
    short8 vn3 = *(const short8*)(vfb + (size_t)(1*4 + cb1)*512);

    f32x4 s0 = __builtin_amdgcn_mfma_f32_16x16x32_bf16(k0, qf, zf, 0, 0, 0);
    f32x4 s1 = __builtin_amdgcn_mfma_f32_16x16x32_bf16(k1, qf, zf, 0, 0, 0);
    f32x4 s2 = __builtin_amdgcn_mfma_f32_16x16x32_bf16(k2, qf, zf, 0, 0, 0);
    f32x4 s3 = __builtin_amdgcn_mfma_f32_16x16x32_bf16(k3, qf, zf, 0, 0, 0);
    {
        unsigned short* pw = &p_scr[0][w][prow + quad*4];
        PAM_DO(pw, 0, s0) PAM_DO(pw, 1, s1) PAM_DO(pw, 2, s2) PAM_DO(pw, 3, s3)
    }
    // K(1)
    k0 = *(const short8*)(kbase + (64 +  0)*8);
    k1 = *(const short8*)(kbase + (64 + 16)*8);
    k2 = *(const short8*)(kbase + (64 + 32)*8);
    k3 = *(const short8*)(kbase + (64 + 48)*8);
    // rotate V: vv = V(0), vn = V(1)
    short8 vv0 = vn0, vv1 = vn1, vv2 = vn2, vv3 = vn3;
    vn0 = *(const short8*)(vfb + (size_t)((2 + 0)*4 + cb0)*512);
    vn1 = *(const short8*)(vfb + (size_t)((2 + 1)*4 + cb0)*512);
    vn2 = *(const short8*)(vfb + (size_t)((2 + 0)*4 + cb1)*512);
    vn3 = *(const short8*)(vfb + (size_t)((2 + 1)*4 + cb1)*512);

    // ---------------- main loop: tc = 1..63; PV lags by one tile -------------
#pragma unroll 2
    for (int tc = 1; tc < NSP/TN; ++tc) {
        const int par = tc & 1;

        // scores(tc) — K(tc) already in regs
        s0 = __builtin_amdgcn_mfma_f32_16x16x32_bf16(k0, qf, zf, 0, 0, 0);
        s1 = __builtin_amdgcn_mfma_f32_16x16x32_bf16(k1, qf, zf, 0, 0, 0);
        s2 = __builtin_amdgcn_mfma_f32_16x16x32_bf16(k2, qf, zf, 0, 0, 0);
        s3 = __builtin_amdgcn_mfma_f32_16x16x32_bf16(k3, qf, zf, 0, 0, 0);

        // prefetch K(tc+1) (wraps at end; used next iteration)
        const int kn = ((tc + 1) & (NSP/TN - 1)) * TN;
        const short8 k0n = *(const short8*)(kbase + (kn +  0)*8);
        const short8 k1n = *(const short8*)(kbase + (kn + 16)*8);
        const short8 k2n = *(const short8*)(kbase + (kn + 32)*8);
        const short8 k3n = *(const short8*)(kbase + (kn + 48)*8);

        // ds_read P(tc-1) — written a full iteration ago; latency covered by
        // the exp/pack VALU below.
        const unsigned short* pr = &p_scr[par ^ 1][w][prow + quad*8];
        const short8 a0 = *(const short8*)pr;          // m 0..31
        const short8 a1 = *(const short8*)(pr + 32);   // m 32..63

        // exp/pack/write(tc) into buffer par
        {
            unsigned short* pw = &p_scr[par][w][prow + quad*4];
            PAM_DO(pw, 0, s0) PAM_DO(pw, 1, s1) PAM_DO(pw, 2, s2) PAM_DO(pw, 3, s3)
        }

        // PV(tc-1) with V(tc-1) = vv
        acc0 = __builtin_amdgcn_mfma_f32_16x16x32_bf16(a0, vv0, acc0, 0, 0, 0);
        acc0 = __builtin_amdgcn_mfma_f32_16x16x32_bf16(a1, vv1, acc0, 0, 0, 0);
        acc1 = __builtin_amdgcn_mfma_f32_16x16x32_bf16(a0, vv2, acc1, 0, 0, 0);
        acc1 = __builtin_amdgcn_mfma_f32_16x16x32_bf16(a1, vv3, acc1, 0, 0, 0);

        // rotate V and prefetch V(tc+1) (wraps; used in PV two iterations out)
        vv0 = vn0; vv1 = vn1; vv2 = vn2; vv3 = vn3;
        const int vt = (tc + 1) & (NSP/TN - 1);
        vn0 = *(const short8*)(vfb + (size_t)((vt*2 + 0)*4 + cb0)*512);
        vn1 = *(const short8*)(vfb + (size_t)((vt*2 + 1)*4 + cb0)*512);
        vn2 = *(const short8*)(vfb + (size_t)((vt*2 + 0)*4 + cb1)*512);
        vn3 = *(const short8*)(vfb + (size_t)((vt*2 + 1)*4 + cb1)*512);

        k0 = k0n; k1 = k1n; k2 = k2n; k3 = k3n;
    }

    // ---------------- pipeline epilogue: PV(63) ----------------
    {
        const unsigned short* pr = &p_scr[1][w][prow + quad*8];   // 63 & 1 = 1
        const short8 a0 = *(const short8*)pr;
        const short8 a1 = *(const short8*)(pr + 32);
        acc0 = __builtin_amdgcn_mfma_f32_16x16x32_bf16(a0, vv0, acc0, 0, 0, 0);
        acc0 = __builtin_amdgcn_mfma_f32_16x16x32_bf16(a1, vv1, acc0, 0, 0, 0);
        acc1 = __builtin_amdgcn_mfma_f32_16x16x32_bf16(a0, vv2, acc1, 0, 0, 0);
        acc1 = __builtin_amdgcn_mfma_f32_16x16x32_bf16(a1, vv3, acc1, 0, 0, 0);
    }
#undef PAM_DO

    // ---- l[q]: sum lane partials over m; lanes q, q+16, q+32, q+48
    lacc += __shfl_xor(lacc, 16);
    lacc += __shfl_xor(lacc, 32);
    if (quad == 0) l_scr[w][row16] = lacc;             // in-wave LDS, no barrier
    const float4 lv = *(const float4*)&l_scr[w][quad*4];

    // ---- epilogue: D layout col=row16=ch-offset, row=quad*4+reg=query-offset
    const float alpha = alpha_p[0];
    const float c0 = alpha / (lv.x + 1e-30f);
    const float c1 = alpha / (lv.y + 1e-30f);
    const float c2 = alpha / (lv.z + 1e-30f);
    const float c3 = alpha / (lv.w + 1e-30f);
#pragma unroll
    for (int cb = 0; cb < 2; ++cb) {
        const int ch = chh*32 + cb*16 + row16;
        const size_t base = (size_t)(b*CH + ch)*NSP + n0w + quad*4;
        const float4 f = *(const float4*)&fm[base];
        const f32x4 a = cb ? acc1 : acc0;
        float4 o;
        o.x = fmaf(c0, a[0], f.x);
        o.y = fmaf(c1, a[1], f.y);
        o.z = fmaf(c2, a[2], f.z);
        o.w = fmaf(c3, a[3], f.w);
        *(float4*)&out[base] = o;
    }
}

// ---------------- launcher ----------------
extern "C" void kernel_launch(void* const* d_in, const int* in_sizes, int n_in,
                              void* d_out, int out_size, void* d_ws, size_t ws_size,
                              hipStream_t stream)
{
    const float* map1  = (const float*)d_in[0];
    const float* map2  = (const float*)d_in[1];
    const float* fm    = (const float*)d_in[2];
    const float* wb    = (const float*)d_in[3];
    const float* bb    = (const float*)d_in[4];
    const float* wc    = (const float*)d_in[5];
    const float* bc    = (const float*)d_in[6];
    const float* wd    = (const float*)d_in[7];
    const float* bd    = (const float*)d_in[8];
    const float* alpha = (const float*)d_in[9];
    float* out = (float*)d_out;

    // ws: featq8 bf16 [4][4096][8] 256KB | featk8 256KB | featdf frag 2MB
    unsigned short* featq8 = (unsigned short*)d_ws;
    unsigned short* featk8 = featq8 + (size_t)BATCH*NSP*8;
    unsigned short* featdf = featk8 + (size_t)BATCH*NSP*8;

    proj_kernel<<<dim3(NSP/64, 2, BATCH), 256, 0, stream>>>(
        map1, map2, fm, wb, bb, wc, bc, wd, bd, featq8, featk8, featdf);
    attn_kernel<<<dim3(NSP/64, 2, BATCH), 256, 0, stream>>>(
        featq8, featk8, featdf, fm, alpha, out);
}